// Round 5
// baseline (17.614 us; speedup 1.0000x reference)
//
#include <hip/hip_runtime.h>
#include <math.h>

#define PMAX 10
#define CCH 515
#define CENTER_CH 514
#define HH 128
#define WW 128
#define HW (HH * WW)
#define VAL_TH 0.3f
#define NTHR 1024
#define CAP 4096
#define PPB 2  // sample points per block

// One fused kernel. Block roles:
//   blocks [0, NV)            : NMS 5x5 (separable, register-blocked) + top-10
//   blocks [NV, NV+NV*PMAX/2) : bilinear grid-sample, 2 points per block
//   block  last               : weighted BCE loss
__global__ __launch_bounds__(NTHR) void fused_kernel(
    const float* __restrict__ fmap, const float* __restrict__ centers,
    const float* __restrict__ logits, const float* __restrict__ labels,
    const float* __restrict__ valid,
    float* __restrict__ out_valk, float* __restrict__ out_nf,
    float* __restrict__ out_loss, int C, int NV, int E) {
    __shared__ float hmv[HW];    // 64 KB: heatmap values
    __shared__ float rmx[HW];    // 64 KB: 5-wide row max
    __shared__ float cand[CAP];  // 16 KB: peak candidates >= TH (loss reuses)
    __shared__ int cnt;
    const int blk = blockIdx.x;
    const int tid = threadIdx.x;
    const int nSample = (NV * PMAX) / PPB;

    if (blk < NV) {
        // ---------- Phase A: load row segment to regs, compute 5-wide row max
        const float* src = fmap + ((size_t)blk * C + CENTER_CH) * HW;
        const int y = tid >> 3;          // 0..127
        const int x0 = (tid & 7) << 4;   // 0,16,...,112
        const float* row = src + y * WW;

        if (tid == 0) cnt = 0;

        float h[20];  // h[k] = hm[y][x0 + k - 2] (cols clamped)
#pragma unroll
        for (int j = 0; j < 4; ++j) {
            const float4 f = *reinterpret_cast<const float4*>(row + x0 + 4 * j);
            h[2 + 4 * j + 0] = f.x; h[2 + 4 * j + 1] = f.y;
            h[2 + 4 * j + 2] = f.z; h[2 + 4 * j + 3] = f.w;
        }
        h[0]  = row[max(x0 - 2, 0)];
        h[1]  = row[max(x0 - 1, 0)];
        h[18] = row[min(x0 + 16, WW - 1)];
        h[19] = row[min(x0 + 17, WW - 1)];

#pragma unroll
        for (int j = 0; j < 4; ++j) {
            *reinterpret_cast<float4*>(&hmv[y * WW + x0 + 4 * j]) =
                float4{h[2+4*j], h[3+4*j], h[4+4*j], h[5+4*j]};
        }

        float p[19];
#pragma unroll
        for (int k = 0; k < 19; ++k) p[k] = fmaxf(h[k], h[k + 1]);
        float rmv[16];
#pragma unroll
        for (int j = 0; j < 16; ++j)
            rmv[j] = fmaxf(fmaxf(p[j], h[j + 2]), p[j + 3]);
#pragma unroll
        for (int j = 0; j < 4; ++j) {
            *reinterpret_cast<float4*>(&rmx[y * WW + x0 + 4 * j]) =
                float4{rmv[4*j], rmv[4*j+1], rmv[4*j+2], rmv[4*j+3]};
        }
        __syncthreads();

        // ---------- Phase B: vertical strip col-max + wave-aggregated compaction
        {
            const int x = tid & 127;
            const int ys = (tid >> 7) << 4;  // 0,16,...,112
            const int lane = tid & 63;
            float m[20];
#pragma unroll
            for (int r = 0; r < 20; ++r)
                m[r] = rmx[min(max(ys + r - 2, 0), HH - 1) * WW + x];
            float pp[19];
#pragma unroll
            for (int r = 0; r < 19; ++r) pp[r] = fmaxf(m[r], m[r + 1]);
#pragma unroll
            for (int j = 0; j < 16; ++j) {
                const float cm = fmaxf(fmaxf(pp[j], m[j + 2]), pp[j + 3]);
                const float v = hmv[(ys + j) * WW + x];
                const bool pred = (cm == v) && (v >= VAL_TH);
                const unsigned long long mask = __ballot(pred);
                if (mask) {
                    const int first = (int)__builtin_ctzll(mask);
                    int base = 0;
                    if (lane == first)
                        base = atomicAdd(&cnt, (int)__popcll(mask));
                    base = __shfl(base, first);
                    if (pred) {
                        const int ofs =
                            base + (int)__popcll(mask & ((1ull << lane) - 1ull));
                        if (ofs < CAP) cand[ofs] = v;
                    }
                }
            }
        }
        __syncthreads();

        // ---------- Phase C: single-wave top-10 (no barriers)
        if (tid < 64) {
            const int n = min(cnt, CAP);
            float t0 = -INFINITY, t1 = -INFINITY, t2 = -INFINITY,
                  t3 = -INFINITY, t4 = -INFINITY, t5 = -INFINITY,
                  t6 = -INFINITY, t7 = -INFINITY, t8 = -INFINITY,
                  t9 = -INFINITY;
            for (int j = tid; j < n; j += 64) {
                float nv = cand[j];
                if (nv > t9) {
                    bool g; float a;
#define INS(tk) a = tk; g = nv > a; tk = g ? nv : a; nv = g ? a : nv;
                    INS(t0) INS(t1) INS(t2) INS(t3) INS(t4)
                    INS(t5) INS(t6) INS(t7) INS(t8) INS(t9)
#undef INS
                }
            }
            for (int r = 0; r < 10; ++r) {
                float bv = t0;
#pragma unroll
                for (int off = 32; off; off >>= 1)
                    bv = fmaxf(bv, __shfl_down(bv, off));
                bv = __shfl(bv, 0);
                const unsigned long long mask = __ballot(t0 == bv);
                const int winner = (int)__builtin_ctzll(mask | 1ull);
                if (tid == winner) {
                    t0 = t1; t1 = t2; t2 = t3; t3 = t4; t4 = t5;
                    t5 = t6; t6 = t7; t7 = t8; t8 = t9; t9 = -INFINITY;
                }
                if (tid == 0)
                    out_valk[blk * PMAX + r] = (bv < VAL_TH) ? 0.0f : bv;
            }
        }
    } else if (blk < NV + nSample) {
        // ---------- bilinear grid-sample: PPB points per block ----------
        // grid-stride over (point, channel) pairs: PPB*C = 1030 > NTHR, so a
        // few threads take a second iteration (fixes R4's tid>=NTHR dropout).
        const int bp0 = (blk - NV) * PPB;
        for (int idx = tid; idx < PPB * C; idx += NTHR) {
            const int p = idx / C;
            const int c = idx - p * C;
            const int bp = bp0 + p;
            const int b = bp / PMAX;

            const float x = centers[bp * 3 + 0];
            const float y = centers[bp * 3 + 1];
            const float x0f = floorf(x), y0f = floorf(y);
            const float wx = x - x0f, wy = y - y0f;
            const int x0 = min(max((int)x0f, 0), WW - 1);
            const int x1 = min(x0 + 1, WW - 1);
            const int y0 = min(max((int)y0f, 0), HH - 1);
            const int y1 = min(y0 + 1, HH - 1);
            const float w00 = (1.0f - wx) * (1.0f - wy);
            const float w01 = wx * (1.0f - wy);
            const float w10 = (1.0f - wx) * wy;
            const float w11 = wx * wy;
            const int o00 = y0 * WW + x0, o01 = y0 * WW + x1;
            const int o10 = y1 * WW + x0, o11 = y1 * WW + x1;
            const float* f = fmap + ((size_t)b * C + c) * HW;
            out_nf[(size_t)bp * C + c] =
                w00 * f[o00] + w01 * f[o01] + w10 * f[o10] + w11 * f[o11];
        }
    } else if (blk == NV + nSample) {
        // ---------- weighted BCE loss (single pass) ----------
        float sp = 0.0f, sv = 0.0f, bpos = 0.0f, bneg = 0.0f;
        for (int i = tid; i < E; i += NTHR) {
            const float xl = logits[i], lab = labels[i], v = valid[i];
            sp += lab * v;
            sv += v;
            const float sm = __logf(1.0f + __expf(-fabsf(xl)));
            const float logp = fminf(xl, 0.0f) - sm;     // log_sigmoid(x)
            const float log1mp = -fmaxf(xl, 0.0f) - sm;  // log_sigmoid(-x)
            const float bce = -(lab * logp + (1.0f - lab) * log1mp);
            const float bv = bce * v;
            if (lab > 0.0f) bpos += bv; else bneg += bv;
        }
        for (int off = 32; off; off >>= 1) {
            sp += __shfl_down(sp, off);
            sv += __shfl_down(sv, off);
            bpos += __shfl_down(bpos, off);
            bneg += __shfl_down(bneg, off);
        }
        const int w = tid >> 6;  // 16 waves
        if ((tid & 63) == 0) {
            cand[w] = sp; cand[16 + w] = sv; cand[32 + w] = bpos; cand[48 + w] = bneg;
        }
        __syncthreads();
        if (tid == 0) {
            float tsp = 0, tsv = 0, tbp = 0, tbn = 0;
            for (int i = 0; i < NTHR / 64; ++i) {
                tsp += cand[i]; tsv += cand[16 + i];
                tbp += cand[32 + i]; tbn += cand[48 + i];
            }
            const float num_neg = tsv - tsp;
            out_loss[0] = tbp / (tsp + 1e-12f) + tbn / (num_neg + 1e-12f);
        }
    }
}

extern "C" void kernel_launch(void* const* d_in, const int* in_sizes, int n_in,
                              void* d_out, int out_size, void* d_ws, size_t ws_size,
                              hipStream_t stream) {
    const float* fmap    = (const float*)d_in[0];
    const float* centers = (const float*)d_in[1];
    const float* logits  = (const float*)d_in[2];
    const float* labels  = (const float*)d_in[3];
    const float* valid   = (const float*)d_in[4];
    float* out = (float*)d_out;

    const int C = CCH;
    const int NV = in_sizes[0] / (C * HW);  // N*V = 10
    const int E = in_sizes[2];              // 2000

    float* out_valk = out;
    float* out_nf   = out + NV * PMAX;
    float* out_loss = out + NV * PMAX + (size_t)NV * PMAX * C;

    const int grid = NV + (NV * PMAX) / PPB + 1;  // 61
    fused_kernel<<<grid, NTHR, 0, stream>>>(fmap, centers, logits, labels, valid,
                                            out_valk, out_nf, out_loss, C, NV, E);
}